// Round 8
// baseline (297.794 us; speedup 1.0000x reference)
//
#include <hip/hip_runtime.h>

#define ROW_LEN 128
#define NPAIR (129 * 129)   // (seq, uniq) pairs, each in [0,128]
#define TBL 1024            // tag-table words per wave (4 KB)

// Kernel A: precompute MLP(feats(seq,uniq)) for all 16641 pairs -> table[p][32].
__global__ __launch_bounds__(256) void mlp_table_kernel(
    const float* __restrict__ W1, const float* __restrict__ b1,
    const float* __restrict__ W2, const float* __restrict__ b2,
    float* __restrict__ table)
{
    const int tid = blockIdx.x * 256 + threadIdx.x;
    if (tid >= NPAIR * 32) return;
    const int p = tid >> 5;
    const int j = tid & 31;
    const int seq  = p / 129;
    const int uniq = p % 129;
    const float f0 = (float)seq  * (1.0f / 128.0f);
    const float f1 = (float)uniq * (1.0f / 128.0f);
    const float f2 = (seq > 0) ? ((float)uniq / (float)seq) : 0.0f;

    float acc = b2[j];
    #pragma unroll
    for (int jj = 0; jj < 32; ++jj) {
        float h = b1[jj];                 // lane-uniform -> scalar loads
        h = fmaf(f0, W1[jj],      h);
        h = fmaf(f1, W1[32 + jj], h);
        h = fmaf(f2, W1[64 + jj], h);
        h = fmaxf(h, 0.0f);
        acc = fmaf(h, W2[jj * 32 + j], acc);
    }
    table[tid] = fmaxf(acc, 0.0f);
}

// Kernel B: persistent waves, one row/wave/iteration, epoch-tagged exchange
// table. Per row the ONLY scattered-LDS traffic is 2 atomicExch (fused
// write+readback). Table zeroed once per wave (amortized over 32 rows).
// Epoch e (1..32) never repeats for a wave's table -> stale entries always
// classified as "old", no re-zeroing needed. Token fits 15 bits (vocab 32000).
// Chain logic per slot: first writer this row sees old epoch -> head (+1);
// later writer seeing same-epoch equal token -> duplicate (drop; its token is
// guaranteed represented); different token -> collision, resolved exactly by
// the ballot verify loop (counts each leftover distinct token once iff it has
// no head). Correct for any data and any HW same-address exchange order.
__global__ __launch_bounds__(256, 8) void rows_kernel(
    const int* __restrict__ ids, const int* __restrict__ amask,
    const float* __restrict__ table, float* __restrict__ out, int B)
{
    __shared__ unsigned tb[4][TBL];

    const int wave = threadIdx.x >> 6;
    const int lane = threadIdx.x & 63;
    unsigned* t = tb[wave];

    // zero own table once: 1024 words / 64 lanes = 4 ds_write_b128 per lane
    uint4* z = (uint4*)t;
    #pragma unroll
    for (int i = 0; i < 4; ++i) z[lane + i * 64] = make_uint4(0u, 0u, 0u, 0u);

    const long gwave   = (long)blockIdx.x * 4 + wave;   // 0..8191
    const long wstride = (long)gridDim.x * 4;           // 8192 waves total

    long row = gwave;
    int2 id2 = make_int2(0, 0), mk2 = make_int2(0, 0);
    if (row < B) {                                      // prefetch iter 0
        id2 = ((const int2*)ids)[row * 64 + lane];
        mk2 = ((const int2*)amask)[row * 64 + lane];
    }

    unsigned e = 1;                                     // epoch: 1..32, 0 = init
    for (; row < B; row += wstride, ++e) {
        // depth-1 prefetch (independent of this row's chain)
        const long nrow = row + wstride;
        int2 id2n = make_int2(0, 0), mk2n = make_int2(0, 0);
        if (nrow < B) {
            id2n = ((const int2*)ids)[nrow * 64 + lane];
            mk2n = ((const int2*)amask)[nrow * 64 + lane];
        }

        const bool mx = (mk2.x != 0);
        const bool my = (mk2.y != 0);
        const unsigned tx = (unsigned)id2.x;            // < 32768 (vocab 32000)
        const unsigned ty = (unsigned)id2.y;
        const unsigned tagx = (e << 15) | tx;
        const unsigned tagy = (e << 15) | ty;

        unsigned rx = 0, ry = 0;
        if (mx) rx = atomicExch(&t[tx & (TBL - 1)], tagx);
        if (my) ry = atomicExch(&t[ty & (TBL - 1)], tagy);

        const bool headx = mx && ((rx >> 15) != e);     // claimed fresh slot
        const bool heady = my && ((ry >> 15) != e);
        const bool dupx  = mx && !headx && ((rx & 0x7FFFu) == tx);
        const bool dupy  = my && !heady && ((ry & 0x7FFFu) == ty);

        const int seq = __popcll(__ballot(mx)) + __popcll(__ballot(my));
        int uniq = __popcll(__ballot(headx)) + __popcll(__ballot(heady));

        // collision losers: same epoch, different token
        unsigned long long p0 = __ballot(mx && !headx && !dupx);
        unsigned long long p1 = __ballot(my && !heady && !dupy);
        while (p0 | p1) {                               // E ~ 2 iterations
            int T;
            if (p0) T = __builtin_amdgcn_readlane(id2.x, __ffsll((long long)p0) - 1);
            else    T = __builtin_amdgcn_readlane(id2.y, __ffsll((long long)p1) - 1);
            const unsigned long long w =
                __ballot((headx && id2.x == T) || (heady && id2.y == T));
            uniq += (w == 0ull);                        // unrepresented: count once
            p0 &= ~__ballot(id2.x == T);                // clear all instances of T
            p1 &= ~__ballot(id2.y == T);
        }

        // epilogue: 128B L2-hot table gather, contiguous 128B store
        const int p = seq * 129 + uniq;
        if (lane < 32) out[row * 32 + lane] = table[p * 32 + lane];

        id2 = id2n;
        mk2 = mk2n;
    }
}

extern "C" void kernel_launch(void* const* d_in, const int* in_sizes, int n_in,
                              void* d_out, int out_size, void* d_ws, size_t ws_size,
                              hipStream_t stream) {
    const int*   ids   = (const int*)d_in[0];
    const int*   amask = (const int*)d_in[1];
    const float* W1    = (const float*)d_in[2];
    const float* b1    = (const float*)d_in[3];
    const float* W2    = (const float*)d_in[4];
    const float* b2    = (const float*)d_in[5];
    float* out   = (float*)d_out;
    float* table = (float*)d_ws;       // NPAIR*32*4 = 2.13 MB of ws

    const int B = in_sizes[0] / ROW_LEN;              // 262144

    const int tblThreads = NPAIR * 32;
    mlp_table_kernel<<<(tblThreads + 255) / 256, 256, 0, stream>>>(W1, b1, W2, b2, table);

    // persistent: 8 blocks/CU x 256 CUs = 2048 blocks (16 KB LDS each),
    // 8192 waves, 32 rows per wave (epoch 1..32)
    rows_kernel<<<2048, 256, 0, stream>>>(ids, amask, table, out, B);
}

// Round 9
// 283.204 us; speedup vs baseline: 1.0515x; 1.0515x over previous
//
#include <hip/hip_runtime.h>

#define ROW_LEN 128
#define NPAIR (129 * 129)   // (seq, uniq) pairs, each in [0,128]

typedef int v4i __attribute__((ext_vector_type(4)));
typedef float v4f __attribute__((ext_vector_type(4)));

// Kernel A: precompute MLP(feats(seq,uniq)) for all 16641 pairs -> table[p][32].
__global__ __launch_bounds__(256) void mlp_table_kernel(
    const float* __restrict__ W1, const float* __restrict__ b1,
    const float* __restrict__ W2, const float* __restrict__ b2,
    float* __restrict__ table)
{
    const int tid = blockIdx.x * 256 + threadIdx.x;
    if (tid >= NPAIR * 32) return;
    const int p = tid >> 5;
    const int j = tid & 31;
    const int seq  = p / 129;
    const int uniq = p % 129;
    const float f0 = (float)seq  * (1.0f / 128.0f);
    const float f1 = (float)uniq * (1.0f / 128.0f);
    const float f2 = (seq > 0) ? ((float)uniq / (float)seq) : 0.0f;

    float acc = b2[j];
    #pragma unroll
    for (int jj = 0; jj < 32; ++jj) {
        float h = b1[jj];                 // lane-uniform -> scalar loads
        h = fmaf(f0, W1[jj],      h);
        h = fmaf(f1, W1[32 + jj], h);
        h = fmaf(f2, W1[64 + jj], h);
        h = fmaxf(h, 0.0f);
        acc = fmaf(h, W2[jj * 32 + j], acc);
    }
    table[tid] = fmaxf(acc, 0.0f);
}

// Kernel B: R4 structure (best so far): two rows per wave, one-shot waves,
// bitmap + atomicOr, ballot reduction. ONE change: nontemporal loads for the
// zero-reuse ids/mask streams and nontemporal store for out, so they do not
// allocate in L2 (testing the L2-thrash hypothesis for the ~2.9 TB/s
// effective input-read ceiling). Table gather stays cached (L2-resident).
__global__ __launch_bounds__(256) void rows_kernel(
    const int* __restrict__ ids, const int* __restrict__ amask,
    const float* __restrict__ table, float* __restrict__ out, int B)
{
    __shared__ unsigned bm[8][1024];   // 2 bitmaps per wave (4 KB each)

    const int wave = threadIdx.x >> 6;
    const int lane = threadIdx.x & 63;
    const int half = lane >> 5;                       // which row of the pair
    const long pair = (long)blockIdx.x * 4 + wave;    // rows 2*pair, 2*pair+1
    if (pair * 2 >= B) return;                        // B % 8 == 0; cosmetic

    // issue nontemporal global loads FIRST so bitmap zeroing overlaps latency.
    // Pair-chunk = 256 ints = 64 int4; lane i covers ints [4i,4i+4).
    const long v = pair * 64 + lane;
    const v4i id4 = __builtin_nontemporal_load((const v4i*)ids + v);
    const v4i mk4 = __builtin_nontemporal_load((const v4i*)amask + v);

    // zero this wave's two bitmaps: 512 uint4 / 64 lanes = 8 ds_write_b128
    uint4* z = (uint4*)bm[wave * 2];
    #pragma unroll
    for (int i = 0; i < 8; ++i) z[lane + i * 64] = make_uint4(0u, 0u, 0u, 0u);

    unsigned* mybm = bm[wave * 2 + half];

    int n0 = 0, n1 = 0, n2 = 0, n3 = 0;   // "new token" flags
    if (mk4.x != 0) {
        const unsigned t = (unsigned)id4.x, m = 1u << (t & 31u);
        n0 = ((atomicOr(&mybm[t >> 5], m) & m) == 0u);
    }
    if (mk4.y != 0) {
        const unsigned t = (unsigned)id4.y, m = 1u << (t & 31u);
        n1 = ((atomicOr(&mybm[t >> 5], m) & m) == 0u);
    }
    if (mk4.z != 0) {
        const unsigned t = (unsigned)id4.z, m = 1u << (t & 31u);
        n2 = ((atomicOr(&mybm[t >> 5], m) & m) == 0u);
    }
    if (mk4.w != 0) {
        const unsigned t = (unsigned)id4.w, m = 1u << (t & 31u);
        n3 = ((atomicOr(&mybm[t >> 5], m) & m) == 0u);
    }

    // wave totals via ballot; low 32 bits = row A lanes, high 32 = row B
    const unsigned long long s0 = __ballot(mk4.x != 0);
    const unsigned long long s1 = __ballot(mk4.y != 0);
    const unsigned long long s2 = __ballot(mk4.z != 0);
    const unsigned long long s3 = __ballot(mk4.w != 0);
    const unsigned long long u0 = __ballot(n0 != 0);
    const unsigned long long u1 = __ballot(n1 != 0);
    const unsigned long long u2 = __ballot(n2 != 0);
    const unsigned long long u3 = __ballot(n3 != 0);

    const int sh = lane & 32;   // 0 for row A lanes, 32 for row B lanes
    const int seq  = __popc((unsigned)(s0 >> sh)) + __popc((unsigned)(s1 >> sh))
                   + __popc((unsigned)(s2 >> sh)) + __popc((unsigned)(s3 >> sh));
    const int uniq = __popc((unsigned)(u0 >> sh)) + __popc((unsigned)(u1 >> sh))
                   + __popc((unsigned)(u2 >> sh)) + __popc((unsigned)(u3 >> sh));

    // epilogue: 128B L2-hot gather per row; contiguous nontemporal 256B store
    const int p = seq * 129 + uniq;
    const float r = table[p * 32 + (lane & 31)];
    __builtin_nontemporal_store(r, out + pair * 64 + lane);
}

extern "C" void kernel_launch(void* const* d_in, const int* in_sizes, int n_in,
                              void* d_out, int out_size, void* d_ws, size_t ws_size,
                              hipStream_t stream) {
    const int*   ids   = (const int*)d_in[0];
    const int*   amask = (const int*)d_in[1];
    const float* W1    = (const float*)d_in[2];
    const float* b1    = (const float*)d_in[3];
    const float* W2    = (const float*)d_in[4];
    const float* b2    = (const float*)d_in[5];
    float* out   = (float*)d_out;
    float* table = (float*)d_ws;       // NPAIR*32*4 = 2.13 MB of ws

    const int B = in_sizes[0] / ROW_LEN;              // 262144

    const int tblThreads = NPAIR * 32;
    mlp_table_kernel<<<(tblThreads + 255) / 256, 256, 0, stream>>>(W1, b1, W2, b2, table);

    // 2 rows per wave, 4 waves per block -> 8 rows per block (R4 structure)
    rows_kernel<<<(B + 7) / 8, 256, 0, stream>>>(ids, amask, table, out, B);
}